// Round 5
// baseline (819.883 us; speedup 1.0000x reference)
//
#include <hip/hip_runtime.h>
#include <math.h>

typedef unsigned short u16;
typedef __bf16 bf16x8 __attribute__((ext_vector_type(8)));
typedef float f32x4 __attribute__((ext_vector_type(4)));
typedef short s16x8 __attribute__((ext_vector_type(8)));

#define DM 2048
#define NB 4
#define SEQ 2048
#define PAST_N 2048
#define CS 4096

__device__ __forceinline__ u16 f2bf(float f) {
  unsigned u = __float_as_uint(f);
  u += 0x7fff + ((u >> 16) & 1);
  return (u16)(u >> 16);
}
__device__ __forceinline__ float bf2f(u16 h) {
  return __uint_as_float(((unsigned)h) << 16);
}

__device__ __forceinline__ void gl_lds16(const u16* g, u16* l) {
  __builtin_amdgcn_global_load_lds(
      (const __attribute__((address_space(1))) unsigned*)g,
      (__attribute__((address_space(3))) unsigned*)l, 16, 0, 0);
}

// Stage this wave's 2 fragment-units (16 rows x 32 k = 1KB each) of one
// 256x32 operand tile into frag-linear LDS. gl_lds writes base+lane*16 (HW);
// the per-lane GLOBAL src realizes the fragment layout: row=lane&15 within
// unit, k-chunk=lane>>4. Consuming ds_read is then unit_base+lane*16 =
// contiguous = conflict-free.
__device__ __forceinline__ void stage_op(const u16* __restrict__ g, int ld,
                                         int ko, u16* sl, int w, int lr, int kh) {
#pragma unroll
  for (int j = 0; j < 2; ++j) {
    const int u = w * 2 + j;  // unit 0..15 = 16-row group
    gl_lds16(g + (long)(u * 16 + lr) * ld + ko + kh * 8, sl + u * 512);
  }
}

// C[M,N] = A[M,K] * B[N,K]^T, bf16 in, fp32 accum. 256x256 tile, BK=32,
// 8 waves (2Mx4N), per-wave 128x64 output = 8x4 16x16 frags.
// LDS: ring-of-3 K-tile slots per operand, frag-linear layout (see stage_op).
// Pipeline: stage lead = 2 tiles; per-tile gate = s_waitcnt vmcnt(4) + raw
// s_barrier (next tile's 4 loads stay in flight across all barriers; vmcnt(0)
// only at the last two gates). Two phases/tile, each {ds_reads + stage ->
// barrier -> lgkmcnt(0) -> setprio(1) 16xMFMA setprio(0)}.
// EPI: 0 = fp32 out, 1 = bf16 out, 2 = both. REMAP: KV-cache row placement.
template <int EPI, bool REMAP>
__global__ __launch_bounds__(512, 2) void gemm256(
    const u16* __restrict__ A, const u16* __restrict__ B,
    float* __restrict__ Cf, u16* __restrict__ Cb, const float* __restrict__ bias,
    int K, int lda, int ldb, int ldc, long strA, long strB, long strC,
    float scale) {
  __shared__ __align__(16) u16 shA[3][256 * 32];  // 3 x 16KB frag-linear
  __shared__ __align__(16) u16 shB[3][256 * 32];
  const int t = threadIdx.x;
  const int lane = t & 63;
  const int w = t >> 6;
  const int wr = w >> 2, wc = w & 3;
  const int lr = lane & 15, kh = lane >> 4;

  // T1: XCD-aware bijective swizzle of flattened block id (nwg % 8 == 0 here)
  const int gx = gridDim.x, gy = gridDim.y;
  const int nwg = gx * gy * gridDim.z;
  const int orig = blockIdx.x + gx * (blockIdx.y + gy * blockIdx.z);
  const int swz = (orig & 7) * (nwg >> 3) + (orig >> 3);
  const int bx = swz % gx;
  const int r1 = swz / gx;
  const int by = r1 % gy;
  const long bz = r1 / gy;
  const int brow = by * 256, bcol = bx * 256;

  const u16* Ab = A + bz * strA + (long)brow * lda;
  const u16* Bb = B + bz * strB + (long)bcol * ldb;

  const int NT = K >> 5;

  // prologue: stage tiles 0 and 1 (8 loads outstanding)
  stage_op(Ab, lda, 0, shA[0], w, lr, kh);
  stage_op(Bb, ldb, 0, shB[0], w, lr, kh);
  if (NT > 1) {
    stage_op(Ab, lda, 32, shA[1], w, lr, kh);
    stage_op(Bb, ldb, 32, shB[1], w, lr, kh);
  }

  f32x4 acc[8][4] = {};
  bf16x8 a[4], b[4];

  for (int tt = 0; tt < NT; ++tt) {
    const int slot = tt % 3;
    const u16* sA = shA[slot];
    const u16* sB = shB[slot];
    const int ns = (tt + 2) % 3;
    const bool st = (tt + 2 < NT);
    const int ko = (tt + 2) << 5;

    // gate: tile tt's 4 loads retired; tile tt+1's 4 stay in flight
    if (tt + 1 < NT)
      asm volatile("s_waitcnt vmcnt(4)" ::: "memory");
    else
      asm volatile("s_waitcnt vmcnt(0)" ::: "memory");
    __builtin_amdgcn_s_barrier();
    __builtin_amdgcn_sched_barrier(0);

    // ---- phase 0: frags for m-half 0 + all B; stage A(tt+2)
#pragma unroll
    for (int mi = 0; mi < 4; ++mi)
      a[mi] = *(const bf16x8*)(sA + (wr * 8 + mi) * 512 + lane * 8);
#pragma unroll
    for (int ni = 0; ni < 4; ++ni)
      b[ni] = *(const bf16x8*)(sB + (wc * 4 + ni) * 512 + lane * 8);
    if (st) stage_op(Ab, lda, ko, shA[ns], w, lr, kh);
    __builtin_amdgcn_s_barrier();
    asm volatile("s_waitcnt lgkmcnt(0)" ::: "memory");
    __builtin_amdgcn_sched_barrier(0);
    __builtin_amdgcn_s_setprio(1);
#pragma unroll
    for (int mi = 0; mi < 4; ++mi)
#pragma unroll
      for (int ni = 0; ni < 4; ++ni)
        acc[mi][ni] = __builtin_amdgcn_mfma_f32_16x16x32_bf16(
            a[mi], b[ni], acc[mi][ni], 0, 0, 0);
    __builtin_amdgcn_s_setprio(0);
    __builtin_amdgcn_s_barrier();

    // ---- phase 1: frags for m-half 1 (B kept in regs); stage B(tt+2)
#pragma unroll
    for (int mi = 0; mi < 4; ++mi)
      a[mi] = *(const bf16x8*)(sA + (wr * 8 + 4 + mi) * 512 + lane * 8);
    if (st) stage_op(Bb, ldb, ko, shB[ns], w, lr, kh);
    asm volatile("s_waitcnt lgkmcnt(0)" ::: "memory");
    __builtin_amdgcn_sched_barrier(0);
    __builtin_amdgcn_s_setprio(1);
#pragma unroll
    for (int mi = 0; mi < 4; ++mi)
#pragma unroll
      for (int ni = 0; ni < 4; ++ni)
        acc[4 + mi][ni] = __builtin_amdgcn_mfma_f32_16x16x32_bf16(
            a[mi], b[ni], acc[4 + mi][ni], 0, 0, 0);
    __builtin_amdgcn_s_setprio(0);
    // next tile's gate barrier closes this tile
  }

  // epilogue: 16x16 C/D layout: col=lane&15, row=(lane>>4)*4 + reg
  const long cb = bz * strC;
#pragma unroll
  for (int mi = 0; mi < 8; ++mi) {
    const int r0 = wr * 128 + mi * 16 + kh * 4;
#pragma unroll
    for (int ni = 0; ni < 4; ++ni) {
      const int c = bcol + wc * 64 + ni * 16 + lr;
      const float bv = bias ? bias[c] : 0.0f;
#pragma unroll
      for (int r = 0; r < 4; ++r) {
        const int row = brow + r0 + r;
        const long orow = REMAP ? (long)((row >> 11) * CS + PAST_N + (row & (SEQ - 1)))
                                : (long)row;
        const float val = (acc[mi][ni][r] + bv) * scale;
        if (EPI == 0 || EPI == 2) Cf[cb + orow * (long)ldc + c] = val;
        if (EPI == 1 || EPI == 2) Cb[cb + orow * (long)ldc + c] = f2bf(val);
      }
    }
  }
}

// fp32 -> bf16 cast, 4 elems/thread
__global__ __launch_bounds__(256) void cast_bf16_kn(const float* __restrict__ in,
                                                    u16* __restrict__ out) {
  const int i = blockIdx.x * 256 + threadIdx.x;
  const float4 v = ((const float4*)in)[i];
  ushort4 o;
  o.x = f2bf(v.x); o.y = f2bf(v.y); o.z = f2bf(v.z); o.w = f2bf(v.w);
  ((ushort4*)out)[i] = o;
}

// past_k/past_v -> cache rows [b, 0..PAST). K path also emits bf16 into kb.
__global__ __launch_bounds__(256) void copy_past_kv(const float* __restrict__ pk,
                                                    const float* __restrict__ pv,
                                                    float* __restrict__ kc,
                                                    float* __restrict__ vc,
                                                    u16* __restrict__ kb) {
  const int i = blockIdx.x * 256 + threadIdx.x;  // < NB*PAST_N*DM/4
  const int d4 = DM / 4;
  const int row = i / d4;
  const int col = i - row * d4;
  const int bb = row >> 11, p = row & (PAST_N - 1);
  const long o = ((long)(bb * CS + p)) * d4 + col;
  if (blockIdx.z == 0) {
    const float4 v = ((const float4*)pk)[i];
    ((float4*)kc)[o] = v;
    ushort4 u;
    u.x = f2bf(v.x); u.y = f2bf(v.y); u.z = f2bf(v.z); u.w = f2bf(v.w);
    ((ushort4*)kb)[o] = u;
  } else {
    ((float4*)vc)[o] = ((const float4*)pv)[i];
  }
}

// v_cache [b][k][d] fp32 -> vT [b][d][k] bf16
__global__ __launch_bounds__(256) void transpose_cast(const float* __restrict__ vcache,
                                                      u16* __restrict__ vt) {
  __shared__ float tile[32][33];
  const int bb = blockIdx.z;
  const int k0 = blockIdx.x * 32, d0 = blockIdx.y * 32;
  const int tx = threadIdx.x & 31, ty = threadIdx.x >> 5;
  const float* src = vcache + (long)bb * CS * DM;
#pragma unroll
  for (int j = 0; j < 4; ++j)
    tile[ty + 8 * j][tx] = src[(long)(k0 + ty + 8 * j) * DM + d0 + tx];
  __syncthreads();
  u16* dst = vt + (long)bb * DM * CS;
#pragma unroll
  for (int j = 0; j < 4; ++j)
    dst[(long)(d0 + ty + 8 * j) * CS + k0 + tx] = f2bf(tile[tx][ty + 8 * j]);
}

// in-place row softmax over bf16 scores, row length CS=4096, one block/row
__global__ __launch_bounds__(256) void softmax_rows(u16* __restrict__ s) {
  const long row = blockIdx.x;
  u16* p = s + row * CS;
  const int t = threadIdx.x;
  const int lane = t & 63, w = t >> 6;
  float v[16];
  s16x8 c0 = ((const s16x8*)p)[t * 2];
  s16x8 c1 = ((const s16x8*)p)[t * 2 + 1];
#pragma unroll
  for (int i = 0; i < 8; ++i) {
    v[i] = bf2f((u16)c0[i]);
    v[8 + i] = bf2f((u16)c1[i]);
  }
  float m = v[0];
#pragma unroll
  for (int i = 1; i < 16; ++i) m = fmaxf(m, v[i]);
#pragma unroll
  for (int o = 32; o >= 1; o >>= 1) m = fmaxf(m, __shfl_xor(m, o, 64));
  __shared__ float red[4];
  if (lane == 0) red[w] = m;
  __syncthreads();
  m = fmaxf(fmaxf(red[0], red[1]), fmaxf(red[2], red[3]));
  float sum = 0.f;
#pragma unroll
  for (int i = 0; i < 16; ++i) {
    v[i] = __expf(v[i] - m);
    sum += v[i];
  }
#pragma unroll
  for (int o = 32; o >= 1; o >>= 1) sum += __shfl_xor(sum, o, 64);
  __syncthreads();
  if (lane == 0) red[w] = sum;
  __syncthreads();
  sum = red[0] + red[1] + red[2] + red[3];
  const float inv = 1.0f / sum;
#pragma unroll
  for (int i = 0; i < 8; ++i) {
    c0[i] = (short)f2bf(v[i] * inv);
    c1[i] = (short)f2bf(v[8 + i] * inv);
  }
  ((s16x8*)p)[t * 2] = c0;
  ((s16x8*)p)[t * 2 + 1] = c1;
}

extern "C" void kernel_launch(void* const* d_in, const int* in_sizes, int n_in,
                              void* d_out, int out_size, void* d_ws, size_t ws_size,
                              hipStream_t stream) {
  const float* x  = (const float*)d_in[0];
  const float* pk = (const float*)d_in[1];
  const float* pv = (const float*)d_in[2];
  const float* Wq = (const float*)d_in[3];
  const float* bq = (const float*)d_in[4];
  const float* Wk = (const float*)d_in[5];
  const float* bk = (const float*)d_in[6];
  const float* Wv = (const float*)d_in[7];
  const float* bv = (const float*)d_in[8];
  const float* Wo = (const float*)d_in[9];
  const float* bo = (const float*)d_in[10];

  float* out = (float*)d_out;
  float* kc = out + (long)NB * SEQ * DM;   // k_cache [4][4096][2048] fp32
  float* vc = kc + (long)NB * CS * DM;     // v_cache

  u16* ws = (u16*)d_ws;
  u16* xb  = ws;              // x bf16 [8192][2048]; reused as attn bf16 later
  u16* wqb = ws + 16777216;
  u16* wkb = wqb + 4194304;
  u16* wvb = wkb + 4194304;
  u16* wob = wvb + 4194304;
  u16* qb  = ws + 33554432;   // q bf16 (scaled) [8192][2048]
  u16* kb  = ws + 50331648;   // k_cache bf16 [4][4096][2048]
  u16* vtb = ws + 83886080;   // v_cache^T bf16 [4][2048][4096]
  u16* sc  = ws + 117440512;  // scores/weights bf16 [4][2048][4096]

  const float qscale = 0.022097086912079608f;  // 1/sqrt(2048)

  cast_bf16_kn<<<16384, 256, 0, stream>>>(x, xb);
  cast_bf16_kn<<<4096, 256, 0, stream>>>(Wq, wqb);
  cast_bf16_kn<<<4096, 256, 0, stream>>>(Wk, wkb);
  cast_bf16_kn<<<4096, 256, 0, stream>>>(Wv, wvb);
  cast_bf16_kn<<<4096, 256, 0, stream>>>(Wo, wob);

  // Q = (x Wq^T + bq) * qscale -> bf16
  gemm256<1, false><<<dim3(8, 32, 1), 512, 0, stream>>>(
      xb, wqb, nullptr, qb, bq, 2048, 2048, 2048, 2048, 0, 0, 0, qscale);
  // K -> fp32 cache + bf16 kb (fused cast)
  gemm256<2, true><<<dim3(8, 32, 1), 512, 0, stream>>>(
      xb, wkb, kc, kb, bk, 2048, 2048, 2048, 2048, 0, 0, 0, 1.0f);
  // V -> fp32 cache
  gemm256<0, true><<<dim3(8, 32, 1), 512, 0, stream>>>(
      xb, wvb, vc, nullptr, bv, 2048, 2048, 2048, 2048, 0, 0, 0, 1.0f);

  copy_past_kv<<<dim3(16384, 1, 2), 256, 0, stream>>>(pk, pv, kc, vc, kb);

  transpose_cast<<<dim3(128, 64, 4), 256, 0, stream>>>(vc, vtb);

  // scores = q_scaled . k_cache^T -> bf16 [4][2048][4096]
  gemm256<1, false><<<dim3(16, 8, 4), 512, 0, stream>>>(
      qb, kb, nullptr, sc, nullptr, 2048, 2048, 2048, 4096,
      2048L * 2048, 4096L * 2048, 2048L * 4096, 1.0f);

  softmax_rows<<<8192, 256, 0, stream>>>(sc);

  // attn = weights . v_cache  (B = vT, K-contiguous) -> bf16 into xb
  gemm256<1, false><<<dim3(8, 8, 4), 512, 0, stream>>>(
      sc, vtb, nullptr, xb, nullptr, 4096, 4096, 4096, 2048,
      2048L * 4096, 2048L * 4096, 2048L * 2048, 1.0f);

  // out = attn Wo^T + bo -> fp32
  gemm256<0, false><<<dim3(8, 32, 1), 512, 0, stream>>>(
      xb, wob, out, nullptr, bo, 2048, 2048, 2048, 2048, 0, 0, 0, 1.0f);
}